// Round 1
// baseline (2980.999 us; speedup 1.0000x reference)
//
#include <hip/hip_runtime.h>
#include <hip/hip_bf16.h>
#include <stdint.h>

// Problem constants
#define B_   64
#define S_   512
#define DIN  512
#define DH   1024
#define KTOT (DIN + DH)      // 1536
#define NBG  4               // batch groups (16 batches each)
#define NCG  32              // col groups (32 cols each)
#define BBLK 16
#define CBLK 32
#define NKC  (KTOT / 32)     // 48 k-chunks of 32

typedef __bf16 bf16x8 __attribute__((ext_vector_type(8)));
typedef float f32x4 __attribute__((ext_vector_type(4)));
typedef unsigned short ushort8v __attribute__((ext_vector_type(8)));
typedef unsigned short ushort4v __attribute__((ext_vector_type(4)));

static __device__ __forceinline__ unsigned short f2bf(float f) {
    union { __bf16 b; unsigned short u; } v; v.b = (__bf16)f; return v.u;
}
static __device__ __forceinline__ float fast_tanh(float x) {
    // 1 - 2/(e^{2x}+1): exact at +/-inf, no NaN from inf/inf
    float e = __expf(2.0f * x);
    return 1.0f - 2.0f / (e + 1.0f);
}

// ---------------- convert x (fp32 -> bf16), 4 elems/thread ----------------
__global__ void k_cvt_bf16(const float* __restrict__ src,
                           unsigned short* __restrict__ dst, int n4) {
    int i = blockIdx.x * blockDim.x + threadIdx.x;
    if (i < n4) {
        float4 v = ((const float4*)src)[i];
        ushort4v o;
        o.x = f2bf(v.x); o.y = f2bf(v.y); o.z = f2bf(v.z); o.w = f2bf(v.w);
        ((ushort4v*)dst)[i] = o;
    }
}

// ------- swizzle W (fp32 [1536][1024]) into B-fragment order, bf16 -------
// layout: [kc(48)][ntg(64)][lane(64)][8] ; frag elem i = W[kc*32+q*8+i][ntg*16+n16]
__global__ void k_swz_w(const float* __restrict__ W,
                        unsigned short* __restrict__ dst) {
    int u = blockIdx.x * blockDim.x + threadIdx.x;   // 48*64*64 = 196608
    int lane = u & 63;
    int ntg  = (u >> 6) & 63;
    int kc   = u >> 12;
    int q = lane >> 4, n16 = lane & 15;
    int k0 = kc * 32 + q * 8;
    int n  = ntg * 16 + n16;
    ushort8v o;
#pragma unroll
    for (int i = 0; i < 8; ++i) o[i] = f2bf(W[(size_t)(k0 + i) * DH + n]);
    *(ushort8v*)(dst + (size_t)u * 8) = o;
}

// ---------------- persistent recurrence kernel ----------------
#define SMEM_A_PITCH 1544                        // 1536 + 8 pad (ushorts)
#define SMEM_A_USH   (16 * SMEM_A_PITCH)         // 24704
#define SMEM_W_USH   (NKC * 2 * 64 * 8)          // 49152
#define SMEM_P_FLT   (4 * 16 * 32)               // 2048
#define SMEM_BYTES   (SMEM_A_USH * 2 + SMEM_W_USH * 2 + SMEM_P_FLT * 4)  // 155904

__global__ __launch_bounds__(256, 1) void k_rnn(
    const unsigned short* __restrict__ xb,    // [B][S][DIN] bf16
    const unsigned short* __restrict__ wswz,  // swizzled W bf16
    const float* __restrict__ h0,             // [B][DH] fp32
    const float* __restrict__ bias,           // [DH] fp32
    float* __restrict__ out,                  // outs [B][S][DH] + h_last [B][DH]
    unsigned int* ring,                       // [2][B][DH/2] bf16-pairs
    int* flags)                               // [NBG][S]
{
    extern __shared__ char smem[];
    unsigned short* ldsA = (unsigned short*)smem;
    unsigned short* ldsW = (unsigned short*)(smem + SMEM_A_USH * 2);
    float* ldsP = (float*)(smem + SMEM_A_USH * 2 + SMEM_W_USH * 2);

    const int tid = threadIdx.x;
    const int bg = blockIdx.x >> 5;
    const int cg = blockIdx.x & 31;
    const int b0 = bg * BBLK;
    const int c0 = cg * CBLK;
    const int lane = tid & 63;
    const int wv = tid >> 6;
    const int q = lane >> 4;
    const int m16 = lane & 15;

    // one-time: preload this WG's W slice (already frag-swizzled, contiguous)
    for (int c = tid; c < NKC * 2 * 64; c += 256) {
        int kc = c >> 7;
        int rem = c & 127;
        int l = rem >> 6;
        int ln = rem & 63;
        size_t src = ((size_t)(kc * 64 + 2 * cg + l) * 64 + ln) * 8;
        int dst = ((kc * 2 + l) * 64 + ln) * 8;
        *(ushort8v*)(ldsW + dst) = *(const ushort8v*)(wswz + src);
    }

    const int em = tid >> 4;          // epilogue row 0..15
    const int np = (tid & 15) * 2;    // epilogue col pair 0..30
    const float bias0 = bias[c0 + np];
    const float bias1 = bias[c0 + np + 1];

    __syncthreads();

    for (int t = 0; t < S_; ++t) {
        // ---- stage x_t -> ldsA[:, 0:512] (doesn't depend on flag)
        ushort8v xs[4];
#pragma unroll
        for (int i = 0; i < 4; ++i) {
            int c = tid + i * 256;
            int row = c >> 6, off = (c & 63) * 8;
            xs[i] = *(const ushort8v*)(xb + ((size_t)(b0 + row) * S_ + t) * DIN + off);
        }
#pragma unroll
        for (int i = 0; i < 4; ++i) {
            int c = tid + i * 256;
            int row = c >> 6, off = (c & 63) * 8;
            *(ushort8v*)(ldsA + row * SMEM_A_PITCH + off) = xs[i];
        }

        // ---- wait for h_{t-1} from the other 31 col-WGs of this batch group
        if (t > 0 && tid == 0) {
            int* f = flags + bg * S_ + (t - 1);
            while (__hip_atomic_load(f, __ATOMIC_RELAXED, __HIP_MEMORY_SCOPE_AGENT) < NCG)
                __builtin_amdgcn_s_sleep(1);
        }
        __syncthreads();

        // ---- stage h_{t-1} -> ldsA[:, 512:1536] (bf16 pairs)
        if (t == 0) {
#pragma unroll
            for (int i = 0; i < 32; ++i) {
                int c = tid + i * 256;
                int row = c >> 9, off2 = c & 511;
                const float2 v = *(const float2*)(h0 + (size_t)(b0 + row) * DH + off2 * 2);
                unsigned int pk = (unsigned int)f2bf(v.x) | ((unsigned int)f2bf(v.y) << 16);
                *(unsigned int*)(ldsA + row * SMEM_A_PITCH + DIN + off2 * 2) = pk;
            }
        } else {
            unsigned int* rg = ring + ((t - 1) & 1) * (B_ * (DH / 2));
            unsigned int hv[32];
#pragma unroll
            for (int i = 0; i < 32; ++i) {           // issue all loads first (ILP)
                int c = tid + i * 256;
                int row = c >> 9, off2 = c & 511;
                hv[i] = __hip_atomic_load(rg + (size_t)(b0 + row) * (DH / 2) + off2,
                                          __ATOMIC_RELAXED, __HIP_MEMORY_SCOPE_AGENT);
            }
#pragma unroll
            for (int i = 0; i < 32; ++i) {
                int c = tid + i * 256;
                int row = c >> 9, off2 = c & 511;
                *(unsigned int*)(ldsA + row * SMEM_A_PITCH + DIN + off2 * 2) = hv[i];
            }
        }
        __syncthreads();

        // ---- MFMA: K-split over 4 waves, 12 k-chunks each, 2 n-tiles
        f32x4 acc0 = {0.f, 0.f, 0.f, 0.f}, acc1 = {0.f, 0.f, 0.f, 0.f};
        const int kcBase = wv * (NKC / 4);
#pragma unroll
        for (int kk = 0; kk < NKC / 4; ++kk) {
            int kc = kcBase + kk;
            bf16x8 a   = *(const bf16x8*)(ldsA + m16 * SMEM_A_PITCH + kc * 32 + q * 8);
            bf16x8 bb0 = *(const bf16x8*)(ldsW + ((kc * 2 + 0) * 64 + lane) * 8);
            bf16x8 bb1 = *(const bf16x8*)(ldsW + ((kc * 2 + 1) * 64 + lane) * 8);
            acc0 = __builtin_amdgcn_mfma_f32_16x16x32_bf16(a, bb0, acc0, 0, 0, 0);
            acc1 = __builtin_amdgcn_mfma_f32_16x16x32_bf16(a, bb1, acc1, 0, 0, 0);
        }
#pragma unroll
        for (int i = 0; i < 4; ++i) {
            ldsP[wv * 512 + (q * 4 + i) * 32 + m16]      = acc0[i];
            ldsP[wv * 512 + (q * 4 + i) * 32 + 16 + m16] = acc1[i];
        }
        __syncthreads();

        // ---- epilogue: reduce 4 wave-partials, bias, tanh, publish
        float s0 = bias0, s1 = bias1;
#pragma unroll
        for (int w = 0; w < 4; ++w) {
            const float2 p = *(const float2*)(ldsP + w * 512 + em * 32 + np);
            s0 += p.x; s1 += p.y;
        }
        float v0 = fast_tanh(s0), v1 = fast_tanh(s1);
        float2 ov; ov.x = v0; ov.y = v1;
        *(float2*)(out + ((size_t)(b0 + em) * S_ + t) * DH + c0 + np) = ov;
        if (t == S_ - 1)
            *(float2*)(out + (size_t)B_ * S_ * DH + (size_t)(b0 + em) * DH + c0 + np) = ov;

        unsigned int pk = (unsigned int)f2bf(v0) | ((unsigned int)f2bf(v1) << 16);
        unsigned int* rw = ring + (t & 1) * (B_ * (DH / 2));
        __hip_atomic_store(rw + (size_t)(b0 + em) * (DH / 2) + (c0 + np) / 2, pk,
                           __ATOMIC_RELAXED, __HIP_MEMORY_SCOPE_AGENT);

        // __syncthreads drains vmcnt(0) for every thread (AGENT stores are
        // write-through-coherent); then one RELEASE add publishes the step.
        __syncthreads();
        if (tid == 0)
            __hip_atomic_fetch_add(flags + bg * S_ + t, 1,
                                   __ATOMIC_RELEASE, __HIP_MEMORY_SCOPE_AGENT);
    }
}

extern "C" void kernel_launch(void* const* d_in, const int* in_sizes, int n_in,
                              void* d_out, int out_size, void* d_ws, size_t ws_size,
                              hipStream_t stream) {
    const float* x  = (const float*)d_in[0];   // [64][512][512]
    const float* h0 = (const float*)d_in[1];   // [64][1024]
    const float* W  = (const float*)d_in[2];   // [1536][1024]
    const float* b  = (const float*)d_in[3];   // [1024]
    float* out = (float*)d_out;

    // workspace layout
    char* ws = (char*)d_ws;
    int* flags = (int*)ws;                                         // 8 KB
    unsigned int* ring = (unsigned int*)(ws + 8192);               // 256 KB
    unsigned short* xb = (unsigned short*)(ws + 8192 + 262144);    // 32 MB
    unsigned short* wswz = xb + (size_t)B_ * S_ * DIN;             // 3 MB

    (void)hipFuncSetAttribute((const void*)k_rnn,
                              hipFuncAttributeMaxDynamicSharedMemorySize,
                              SMEM_BYTES);

    hipMemsetAsync(flags, 0, NBG * S_ * sizeof(int), stream);
    k_cvt_bf16<<<(B_ * S_ * DIN / 4 + 255) / 256, 256, 0, stream>>>(x, xb, B_ * S_ * DIN / 4);
    k_swz_w<<<(NKC * 64 * 64) / 256, 256, 0, stream>>>(W, wswz);
    k_rnn<<<NBG * NCG, 256, SMEM_BYTES, stream>>>(xb, wswz, h0, b, out, ring, flags);
}